// Round 5
// baseline (39.373 us; speedup 1.0000x reference)
//
#include <hip/hip_runtime.h>
#include <math.h>

namespace {

constexpr int Bn = 8;
constexpr int Hn = 256;
constexpr int Wn = 256;
constexpr int HW = Hn * Wn;       // 65536
constexpr int Ntot = Bn * HW;     // 524288
constexpr float INF_F = 131138.0f; // sum(n*n for n in shape)+1
constexpr float EPSv = 1e-6f;

// 256-thread block sum; returns full sum to all threads. Fixed order -> deterministic.
__device__ __forceinline__ float blkred(float v, float* sm) {
    #pragma unroll
    for (int o = 32; o > 0; o >>= 1) v += __shfl_down(v, o, 64);
    int lane = threadIdx.x & 63, wid = threadIdx.x >> 6;
    __syncthreads();
    if (lane == 0) sm[wid] = v;
    __syncthreads();
    return sm[0] + sm[1] + sm[2] + sm[3];
}

// Wave-cooperative exact 1D DT over a 256-line staged in LDS as
// u[j] = f[j] + j^2:  res(i) = i^2 + min_j (u[j] - 2*j*i).
// All intermediates exact integers < 2^24 -> bit-identical to brute force.
// Lane l computes i in {4l..4l+3}. 8 min chains/lane; fminf pairs -> v_min3.
__device__ __forceinline__ void dt_wave4(const float* __restrict__ u,
                                         int lane, float res[4]) {
    const float4* u4 = reinterpret_cast<const float4*>(u);
    float fi[4], mA[4], mB[4];
    #pragma unroll
    for (int r = 0; r < 4; ++r) {
        fi[r] = (float)(4 * lane + r);
        mA[r] = 3.0e38f; mB[r] = 3.0e38f;
    }
    #pragma unroll 8
    for (int q = 0; q < 64; ++q) {
        float4 uu = u4[q];             // wave-uniform broadcast read
        float j0 = (float)(-2 * (4 * q + 0));
        float j1 = (float)(-2 * (4 * q + 1));
        float j2 = (float)(-2 * (4 * q + 2));
        float j3 = (float)(-2 * (4 * q + 3));
        #pragma unroll
        for (int r = 0; r < 4; ++r) {
            mA[r] = fminf(fminf(mA[r], fmaf(j0, fi[r], uu.x)),
                          fmaf(j1, fi[r], uu.y));
            mB[r] = fminf(fminf(mB[r], fmaf(j2, fi[r], uu.z)),
                          fmaf(j3, fi[r], uu.w));
        }
    }
    #pragma unroll
    for (int r = 0; r < 4; ++r)
        res[r] = fminf(mA[r], mB[r]) + fi[r] * fi[r];
}

// Kernel A: per-(h,w) pixel, loop batches. Sigmoid + dice/focal partials,
// axis-B DT (n=8) in regs. Also arms kH's election counter.
__global__ __launch_bounds__(256) void kA(const float* __restrict__ lg,
                                          const float* __restrict__ tg,
                                          float* __restrict__ f1,
                                          float* __restrict__ pa,
                                          unsigned int* __restrict__ cnt) {
    if (blockIdx.x == 0 && threadIdx.x == 0) *cnt = 0u;
    int t = blockIdx.x * 256 + threadIdx.x;   // 0..HW-1
    float sp = 0.f, st = 0.f, spt = 0.f, fo = 0.f;
    float fv[Bn];
    #pragma unroll
    for (int b = 0; b < Bn; b++) {
        float x  = lg[b * HW + t];
        float tv = tg[b * HW + t];
        float p  = 1.f / (1.f + expf(-x));
        sp  += p;
        st  += tv;
        spt += p * tv;
        float ce = fmaxf(x, 0.f) - x * tv + log1pf(expf(-fabsf(x)));
        float pt = p * tv + (1.f - p) * (1.f - tv);
        float om = 1.f - pt;
        fo += 0.25f * om * om * ce;          // ALPHA=0.25, GAMMA=2
        fv[b] = (tv > 0.5f) ? INF_F : 0.f;
    }
    // exact 1D squared-distance transform along batch axis (n=8)
    #pragma unroll
    for (int i = 0; i < Bn; i++) {
        float m = fv[0] + (float)(i * i);
        #pragma unroll
        for (int j = 1; j < Bn; j++) {
            int d = i - j;
            m = fminf(m, fv[j] + (float)(d * d));
        }
        f1[i * HW + t] = m;
    }
    __shared__ float sm[4];
    sp  = blkred(sp, sm);
    st  = blkred(st, sm);
    spt = blkred(spt, sm);
    fo  = blkred(fo, sm);
    if (threadIdx.x == 0) {
        float* o = pa + blockIdx.x * 4;
        o[0] = sp; o[1] = st; o[2] = spt; o[3] = fo;
    }
}

// Kernel W: DT along W. 4 lines/block, one per wave; float4 coalesced I/O.
__global__ __launch_bounds__(256) void kW(const float* __restrict__ f1,
                                          float* __restrict__ g) {
    __shared__ __align__(16) float u[4][Wn];
    int wv = threadIdx.x >> 6, lane = threadIdx.x & 63;
    int line = blockIdx.x * 4 + wv;        // b*Hn + h
    float4 v = reinterpret_cast<const float4*>(f1 + (size_t)line * Wn)[lane];
    float j0 = (float)(4 * lane);
    v.x += j0 * j0;
    v.y += (j0 + 1.f) * (j0 + 1.f);
    v.z += (j0 + 2.f) * (j0 + 2.f);
    v.w += (j0 + 3.f) * (j0 + 3.f);
    reinterpret_cast<float4*>(u[wv])[lane] = v;
    __syncthreads();
    float res[4];
    dt_wave4(u[wv], lane, res);
    float4 o = make_float4(res[0], res[1], res[2], res[3]);
    reinterpret_cast<float4*>(g + (size_t)line * Wn)[lane] = o;
}

// Kernel H: DT along H. Block = 4 adjacent (b,w) columns; slab-load g and lg
// with strided float4s (L2/L3-resident), LDS-transpose, wave-per-line DT,
// fused sqrt * (1-p)^2 + block reduce. Last-arriving block does the final
// combine (fixed-order sums -> bit-deterministic regardless of which block).
__global__ __launch_bounds__(256) void kH(const float* __restrict__ g,
                                          const float* __restrict__ lg,
                                          const float* __restrict__ pa,
                                          float* __restrict__ bp,
                                          unsigned int* __restrict__ cnt,
                                          float* __restrict__ out,
                                          int nblocks) {
    __shared__ __align__(16) float u[4][Hn];
    __shared__ __align__(16) float xs[4][Hn];
    __shared__ float sm[4];
    __shared__ unsigned int tick;
    int tid = threadIdx.x;
    int wv = tid >> 6, lane = tid & 63;
    int b  = blockIdx.x >> 6;              // 512 blocks: 64 per batch
    int w0 = (blockIdx.x & 63) * 4;
    const float* gb = g  + (size_t)b * HW + w0;
    const float* lb = lg + (size_t)b * HW + w0;
    float4 gv = *reinterpret_cast<const float4*>(gb + (size_t)tid * Wn);
    float4 xv = *reinterpret_cast<const float4*>(lb + (size_t)tid * Wn);
    float h2 = (float)tid * (float)tid;
    u[0][tid] = gv.x + h2; u[1][tid] = gv.y + h2;
    u[2][tid] = gv.z + h2; u[3][tid] = gv.w + h2;
    xs[0][tid] = xv.x; xs[1][tid] = xv.y; xs[2][tid] = xv.z; xs[3][tid] = xv.w;
    __syncthreads();
    float res[4];
    dt_wave4(u[wv], lane, res);
    float acc = 0.f;
    #pragma unroll
    for (int r = 0; r < 4; ++r) {
        int i = 4 * lane + r;
        float x = xs[wv][i];
        float s = 1.f / (1.f + expf(x));   // = 1 - sigmoid(x)
        acc += sqrtf(res[r]) * s * s;
    }
    acc = blkred(acc, sm);
    if (tid == 0) {
        bp[blockIdx.x] = acc;
        __threadfence();                   // release bp before ticket
        tick = atomicAdd(cnt, 1u);
    }
    __syncthreads();
    if (tick == (unsigned int)(nblocks - 1)) {
        __threadfence();                   // acquire all blocks' bp
        float sp  = pa[tid * 4 + 0];
        float st  = pa[tid * 4 + 1];
        float spt = pa[tid * 4 + 2];
        float fo  = pa[tid * 4 + 3];
        float bs  = bp[tid] + bp[tid + 256];
        sp  = blkred(sp, sm);
        st  = blkred(st, sm);
        spt = blkred(spt, sm);
        fo  = blkred(fo, sm);
        bs  = blkred(bs, sm);
        if (tid == 0) {
            float dice = 1.f - (2.f * spt + EPSv) / (sp + st + EPSv);
            float boundary = bs / (float)Ntot;
            float focal = fo / (float)Ntot;
            out[0] = 1.0f * dice + 0.5f * boundary + 1.0f * focal;
            *cnt = 0u;                     // re-arm for next call
        }
    }
}

} // namespace

extern "C" void kernel_launch(void* const* d_in, const int* in_sizes, int n_in,
                              void* d_out, int out_size, void* d_ws, size_t ws_size,
                              hipStream_t stream) {
    const float* lg = (const float*)d_in[0];   // logits  [8,1,256,256] f32
    const float* tg = (const float*)d_in[1];   // targets [8,1,256,256] f32
    float* ws = (float*)d_ws;
    float* f1 = ws;                        // [b][h][w] post B-DT
    float* g  = ws + Ntot;                 // [b][h][w] post W-DT
    float* pa = ws + 2 * Ntot;             // 256 blocks * 4 partials
    float* bp = ws + 2 * Ntot + 1024;      // 512 boundary partials
    unsigned int* cnt = (unsigned int*)(ws + 2 * Ntot + 2048);

    kA<<<HW / 256, 256, 0, stream>>>(lg, tg, f1, pa, cnt);
    kW<<<Bn * Hn / 4, 256, 0, stream>>>(f1, g);
    kH<<<Bn * Wn / 4, 256, 0, stream>>>(g, lg, pa, bp, cnt, (float*)d_out,
                                        Bn * Wn / 4);
}